// Round 3
// baseline (224.771 us; speedup 1.0000x reference)
//
#include <hip/hip_runtime.h>
#include <stdint.h>

// ---- problem constants ----
constexpr int NBASES = 32;
constexpr int NKP    = 17;
constexpr int HDIM   = 100, WDIM = 152;
constexpr int HW     = HDIM * WDIM;       // 15200
constexpr int NI     = 64;
constexpr int KF     = 2304;
constexpr int AL     = 2737;
constexpr int ALP    = 2740;              // padded per-instance stride (16B-aligned rows)
// packed reference offsets inside an attns row
constexpr int OB0 = 1088;
constexpr int OW1 = 1120;
constexpr int OB1 = 2144;
constexpr int OW2 = 2176;
constexpr int OB2 = 2720;
// permuted layout (w0/w1 c-major; w2 k-major)
constexpr int TW0 = 0;      // [34][32]
constexpr int TB0 = 1088;   // 32
constexpr int TW1 = 1120;   // [32][32]
constexpr int TB1 = 2144;   // 32
constexpr int TW2 = 2176;   // [17][32]
constexpr int TB2 = 2720;   // 17

constexpr int PXB = 512;                     // pixels per block (512 thr x 1 px)
constexpr int NBX = (HW + PXB - 1) / PXB;    // 30

// gemm tiling
constexpr int JT     = 64;
constexpr int KCH    = 64;
constexpr int KSPLIT = 12;             // KT = 192 -> 516 blocks (~2/CU)
constexpr int KT     = KF / KSPLIT;
constexpr int NJT    = (AL + JT - 1) / JT;  // 43
constexpr int JTOT   = NJT * JT;            // 2752
constexpr int LPAD   = 68;

// ws layout (bytes)
constexpr size_t ATT_OFF   = 0;                                  // NI*ALP*4   = 701,440
constexpr size_t ARGP_OFF  = (size_t)NI * ALP * 4;               // 701,440
constexpr size_t GEMMP_OFF = ARGP_OFF + (size_t)NI * NKP * NBX * 8;  // 962,560
// gemm partial size: KSPLIT*NI*JTOT*4 = 8,454,144 -> total ~9.4 MB

__device__ __forceinline__ int perm(int j) {
    if (j < OB0)      { int o = j / 34, c = j - o * 34; return TW0 + c * 32 + o; }
    else if (j < OW1) return TB0 + (j - OB0);
    else if (j < OB1) { int q = j - OW1; int o = q >> 5, c = q & 31; return TW1 + c * 32 + o; }
    else if (j < OW2) return TB1 + (j - OB1);
    else if (j < OB2) return TW2 + (j - OW2);
    else              return TB2 + (j - OB2);
}

// ========== kernel 1: attns GEMM partials (no atomics) ==========
__global__ __launch_bounds__(256) void gemm_attn(const float* __restrict__ tf,
                                                 const float* __restrict__ W,
                                                 float* __restrict__ partial) {
    __shared__ __align__(16) float Tl[KCH][LPAD];
    __shared__ __align__(16) float Wl[KCH][LPAD];
    int jb = blockIdx.x % NJT;
    int ks = blockIdx.x / NJT;
    int j0 = jb * JT;
    int k0 = ks * KT;
    int tid = threadIdx.x;
    int tn = tid % 16;
    int tj = tid / 16;
    int lk = tid % 64;
    int lr = tid / 64;
    float acc[4][4] = {};
    for (int kc = 0; kc < KT; kc += KCH) {
        int kbase = k0 + kc;
        #pragma unroll
        for (int i = 0; i < 16; i++) {
            int nn = lr * 16 + i;
            Tl[lk][nn] = tf[(size_t)nn * KF + kbase + lk];
        }
        #pragma unroll
        for (int i = 0; i < 16; i++) {
            int j = j0 + lr * 16 + i;
            Wl[lk][lr * 16 + i] = (j < AL) ? W[(size_t)j * KF + kbase + lk] : 0.0f;
        }
        __syncthreads();
        #pragma unroll 4
        for (int kk = 0; kk < KCH; ++kk) {
            float tv[4], wv[4];
            #pragma unroll
            for (int i = 0; i < 4; i++) tv[i] = Tl[kk][tn * 4 + i];
            #pragma unroll
            for (int i = 0; i < 4; i++) wv[i] = Wl[kk][tj * 4 + i];
            #pragma unroll
            for (int i = 0; i < 4; i++)
                #pragma unroll
                for (int q = 0; q < 4; q++) acc[i][q] += tv[i] * wv[q];
        }
        __syncthreads();
    }
    // plain stores to disjoint per-ks partials (float4, 16B-aligned)
    size_t pbase = (size_t)(ks * NI) * JTOT;
    #pragma unroll
    for (int i = 0; i < 4; i++) {
        int nn = tn * 4 + i;
        int j = j0 + tj * 4;
        float4 st = make_float4(acc[i][0], acc[i][1], acc[i][2], acc[i][3]);
        *(float4*)&partial[pbase + (size_t)nn * JTOT + j] = st;
    }
}

// ========== kernel 2: reduce partials + bias -> permuted att_p ==========
__global__ __launch_bounds__(256) void reduce_attn(const float* __restrict__ partial,
                                                   const float* __restrict__ b,
                                                   float* __restrict__ att_p) {
    int n = blockIdx.y;
    int j = blockIdx.x * 256 + threadIdx.x;
    if (j >= AL) return;
    float s = b[j];
    #pragma unroll
    for (int ks = 0; ks < KSPLIT; ks++)
        s += partial[(size_t)(ks * NI + n) * JTOT + j];
    att_p[(size_t)n * ALP + perm(j)] = s;
}

// ========== kernel 3: fused per-pixel head + block argmax ==========
// All weights are block-uniform (depend only on n = blockIdx.y) -> read them
// through the uniform global pointer so the compiler scalarizes to s_load and
// folds SGPR operands straight into v_fmac. Zero LDS / zero VMEM for weights.
__device__ inline unsigned int mono_f32(float f) {
    unsigned int u = __float_as_uint(f);
    return (u & 0x80000000u) ? ~u : (u | 0x80000000u);
}

__global__ __launch_bounds__(512, 8) void pixel_head(const float* __restrict__ bases_full,
                                                     const float* __restrict__ att_p,
                                                     const float* __restrict__ locations,
                                                     const float* __restrict__ soi,
                                                     const int* __restrict__ fpn,
                                                     float* __restrict__ out_logits,
                                                     unsigned long long* __restrict__ partial) {
    __shared__ unsigned long long red[8][NKP];
    int n = blockIdx.y, bx = blockIdx.x, tid = threadIdx.x;
    const float* wn = att_p + (size_t)n * ALP;       // block-uniform base

    int p0 = bx * PXB + tid;
    bool valid = p0 < HW;
    int pc = valid ? p0 : 0;
    int y = pc / WDIM, x = pc - y * WDIM;

    float inv = 1.0f / soi[fpn[n]];
    float lx = locations[2 * n], ly = locations[2 * n + 1];
    float cx = (lx - (float)(x * 8 + 4)) * inv;
    float cy = (ly - (float)(y * 8 + 4)) * inv;

    // issue first bases loads early so latency hides under the offsets FMAs
    const float* bp = bases_full + pc;
    float q0 = bp[0], q1 = bp[HW], q2 = bp[2 * (size_t)HW], q3 = bp[3 * (size_t)HW];

    // ---- layer 0: h = relu(W0 x + b0), c-outer streaming, scalar weights ----
    float h[32];
    {
        const float4* br  = (const float4*)(wn + TB0);
        const float4* w0r = (const float4*)(wn + TW0);
        const float4* w1r = (const float4*)(wn + TW0 + 32);
        #pragma unroll
        for (int g = 0; g < 8; g++) {
            float4 b4 = br[g], wv = w0r[g], wu = w1r[g];
            h[4*g+0] = b4.x + wv.x * cx + wu.x * cy;
            h[4*g+1] = b4.y + wv.y * cx + wu.y * cy;
            h[4*g+2] = b4.z + wv.z * cx + wu.z * cy;
            h[4*g+3] = b4.w + wv.w * cx + wu.w * cy;
        }
    }
    // 4-deep rolling prefetch over the 32 bases channels
    #pragma unroll 2
    for (int c0 = 0; c0 < 32; c0 += 4) {
        float n0 = 0.f, n1 = 0.f, n2 = 0.f, n3 = 0.f;
        if (c0 + 4 < 32) {
            n0 = bp[(size_t)(c0 + 4) * HW];
            n1 = bp[(size_t)(c0 + 5) * HW];
            n2 = bp[(size_t)(c0 + 6) * HW];
            n3 = bp[(size_t)(c0 + 7) * HW];
        }
        float qq[4] = {q0, q1, q2, q3};
        #pragma unroll
        for (int u = 0; u < 4; u++) {
            float bv = qq[u];
            const float4* wr = (const float4*)(wn + TW0 + (c0 + u + 2) * 32);
            #pragma unroll
            for (int g = 0; g < 8; g++) {
                float4 wv = wr[g];
                h[4*g+0] += wv.x * bv;
                h[4*g+1] += wv.y * bv;
                h[4*g+2] += wv.z * bv;
                h[4*g+3] += wv.w * bv;
            }
        }
        q0 = n0; q1 = n1; q2 = n2; q3 = n3;
    }
    #pragma unroll
    for (int o = 0; o < 32; o++) h[o] = fmaxf(h[o], 0.0f);

    // ---- layer 1: scalar weights via uniform global pointer ----
    float gg[32];
    {
        const float4* br = (const float4*)(wn + TB1);
        #pragma unroll
        for (int g = 0; g < 8; g++) {
            float4 b4 = br[g];
            gg[4*g+0] = b4.x; gg[4*g+1] = b4.y; gg[4*g+2] = b4.z; gg[4*g+3] = b4.w;
        }
    }
    #pragma unroll 4
    for (int c = 0; c < 32; c++) {
        float xv = h[c];
        const float4* wr = (const float4*)(wn + TW1 + c * 32);
        #pragma unroll
        for (int g = 0; g < 8; g++) {
            float4 wv = wr[g];
            gg[4*g+0] += wv.x * xv;
            gg[4*g+1] += wv.y * xv;
            gg[4*g+2] += wv.z * xv;
            gg[4*g+3] += wv.w * xv;
        }
    }
    #pragma unroll
    for (int o = 0; o < 32; o++) gg[o] = fmaxf(gg[o], 0.0f);

    // ---- layer 2: scalar weights; store logits + fused per-k argmax ----
    // Wave argmax: 32-bit fp max butterfly, then ballot + ffs for the winning
    // lane (lowest lane = smallest pixel index = numpy first-occurrence).
    size_t obase = (size_t)n * NKP * HW;
    int wid = tid >> 6, lane = tid & 63;
    #pragma unroll
    for (int k = 0; k < NKP; k++) {
        const float4* wr = (const float4*)(wn + TW2 + k * 32);
        float s = wn[TB2 + k];
        #pragma unroll
        for (int g = 0; g < 8; g++) {
            float4 wv = wr[g];
            s += wv.x * gg[4*g+0] + wv.y * gg[4*g+1] + wv.z * gg[4*g+2] + wv.w * gg[4*g+3];
        }
        if (valid)
            __builtin_nontemporal_store(s, &out_logits[obase + (size_t)k * HW + p0]);
        float sm = valid ? s : -__builtin_inff();
        float m = sm;
        #pragma unroll
        for (int off = 32; off > 0; off >>= 1)
            m = fmaxf(m, __shfl_xor(m, off));
        unsigned long long ball = __ballot(sm == m);
        if (lane == 0) {
            int winlane = __ffsll((unsigned long long)ball) - 1;
            unsigned pix = (unsigned)(bx * PXB + (wid << 6) + winlane);
            red[wid][k] = ((unsigned long long)mono_f32(m) << 32) |
                          (unsigned long long)(0xFFFFFFFFu - pix);
        }
    }
    __syncthreads();
    if (tid < NKP) {
        unsigned long long m = red[0][tid];
        #pragma unroll
        for (int ww = 1; ww < 8; ww++)
            if (red[ww][tid] > m) m = red[ww][tid];
        partial[((size_t)n * NKP + tid) * NBX + bx] = m;
    }
}

// ========== kernel 4: final argmax reduce + keypoint ==========
__global__ __launch_bounds__(64) void kp_final(const unsigned long long* __restrict__ partial,
                                               const float* __restrict__ bases_full,
                                               float* __restrict__ kp_out) {
    int b = blockIdx.x;
    int n = b / NKP, k = b % NKP;
    int lane = threadIdx.x;
    unsigned long long v = (lane < NBX) ? partial[((size_t)n * NKP + k) * NBX + lane] : 0ull;
    #pragma unroll
    for (int off = 32; off > 0; off >>= 1) {
        unsigned long long o = __shfl_down(v, off);
        if (o > v) v = o;
    }
    if (lane == 0) {
        int p = (int)(0xFFFFFFFFu - (unsigned)(v & 0xFFFFFFFFull));
        int yy = p / WDIM;
        int xx = p - yy * WDIM;
        float kx = bases_full[(size_t)(NBASES + 2 * k) * HW + p] + (float)(xx * 8 + 4);
        float ky = bases_full[(size_t)(NBASES + 2 * k + 1) * HW + p] + (float)(yy * 8 + 4);
        kp_out[((size_t)n * NKP + k) * 2 + 0] = kx;
        kp_out[((size_t)n * NKP + k) * 2 + 1] = ky;
    }
}

extern "C" void kernel_launch(void* const* d_in, const int* in_sizes, int n_in,
                              void* d_out, int out_size, void* d_ws, size_t ws_size,
                              hipStream_t stream) {
    const float* bases_full = (const float*)d_in[0];
    const float* top_feats  = (const float*)d_in[1];
    const float* locations  = (const float*)d_in[2];
    const float* atten_W    = (const float*)d_in[3];
    const float* atten_b    = (const float*)d_in[4];
    const float* soi        = (const float*)d_in[5];
    const int*   fpn        = (const int*)d_in[6];
    float* out   = (float*)d_out;
    float* att_p = (float*)((char*)d_ws + ATT_OFF);
    unsigned long long* argp = (unsigned long long*)((char*)d_ws + ARGP_OFF);
    float* gemmp = (float*)((char*)d_ws + GEMMP_OFF);

    gemm_attn<<<NJT * KSPLIT, 256, 0, stream>>>(top_feats, atten_W, gemmp);

    dim3 gr((AL + 255) / 256, NI);   // 11 x 64
    reduce_attn<<<gr, 256, 0, stream>>>(gemmp, atten_b, att_p);

    dim3 g2(NBX, NI);   // 30 x 64
    pixel_head<<<g2, 512, 0, stream>>>(bases_full, att_p, locations, soi, fpn, out, argp);

    float* kp_out = out + (size_t)NI * NKP * HW;
    kp_final<<<NI * NKP, 64, 0, stream>>>(argp, bases_full, kp_out);
}

// Round 4
// 208.205 us; speedup vs baseline: 1.0796x; 1.0796x over previous
//
#include <hip/hip_runtime.h>
#include <stdint.h>

// ---- problem constants ----
constexpr int NBASES = 32;
constexpr int NKP    = 17;
constexpr int HDIM   = 100, WDIM = 152;
constexpr int HW     = HDIM * WDIM;       // 15200
constexpr int NI     = 64;
constexpr int KF     = 2304;
constexpr int AL     = 2737;
constexpr int ALP    = 2740;              // padded per-instance stride (16B-aligned rows)
// packed reference offsets inside an attns row
constexpr int OB0 = 1088;
constexpr int OW1 = 1120;
constexpr int OB1 = 2144;
constexpr int OW2 = 2176;
constexpr int OB2 = 2720;
// permuted layout (w0/w1 c-major; w2 k-major)
constexpr int TW0 = 0;      // [34][32]
constexpr int TB0 = 1088;   // 32
constexpr int TW1 = 1120;   // [32][32]
constexpr int TB1 = 2144;   // 32
constexpr int TW2 = 2176;   // [17][32]
constexpr int TB2 = 2720;   // 17

constexpr int PXB = 512;                     // pixels per block (512 thr x 1 px)
constexpr int NBX = (HW + PXB - 1) / PXB;    // 30

// gemm tiling
constexpr int JT     = 64;
constexpr int KCH    = 64;
constexpr int KSPLIT = 12;             // KT = 192 -> 516 blocks (~2/CU)
constexpr int KT     = KF / KSPLIT;
constexpr int NJT    = (AL + JT - 1) / JT;  // 43
constexpr int JTOT   = NJT * JT;            // 2752
constexpr int LPAD   = 68;

// ws layout (bytes)
constexpr size_t ATT_OFF   = 0;                                  // NI*ALP*4   = 701,440
constexpr size_t ARGP_OFF  = (size_t)NI * ALP * 4;               // 701,440
constexpr size_t GEMMP_OFF = ARGP_OFF + (size_t)NI * NKP * NBX * 8;  // 962,560
// gemm partial size: KSPLIT*NI*JTOT*4 = 8,454,144 -> total ~9.4 MB

__device__ __forceinline__ int perm(int j) {
    if (j < OB0)      { int o = j / 34, c = j - o * 34; return TW0 + c * 32 + o; }
    else if (j < OW1) return TB0 + (j - OB0);
    else if (j < OB1) { int q = j - OW1; int o = q >> 5, c = q & 31; return TW1 + c * 32 + o; }
    else if (j < OW2) return TB1 + (j - OB1);
    else if (j < OB2) return TW2 + (j - OW2);
    else              return TB2 + (j - OB2);
}

// ========== kernel 1: attns GEMM partials (no atomics) ==========
__global__ __launch_bounds__(256) void gemm_attn(const float* __restrict__ tf,
                                                 const float* __restrict__ W,
                                                 float* __restrict__ partial) {
    __shared__ __align__(16) float Tl[KCH][LPAD];
    __shared__ __align__(16) float Wl[KCH][LPAD];
    int jb = blockIdx.x % NJT;
    int ks = blockIdx.x / NJT;
    int j0 = jb * JT;
    int k0 = ks * KT;
    int tid = threadIdx.x;
    int tn = tid % 16;
    int tj = tid / 16;
    int lk = tid % 64;
    int lr = tid / 64;
    float acc[4][4] = {};
    for (int kc = 0; kc < KT; kc += KCH) {
        int kbase = k0 + kc;
        #pragma unroll
        for (int i = 0; i < 16; i++) {
            int nn = lr * 16 + i;
            Tl[lk][nn] = tf[(size_t)nn * KF + kbase + lk];
        }
        #pragma unroll
        for (int i = 0; i < 16; i++) {
            int j = j0 + lr * 16 + i;
            Wl[lk][lr * 16 + i] = (j < AL) ? W[(size_t)j * KF + kbase + lk] : 0.0f;
        }
        __syncthreads();
        #pragma unroll 4
        for (int kk = 0; kk < KCH; ++kk) {
            float tv[4], wv[4];
            #pragma unroll
            for (int i = 0; i < 4; i++) tv[i] = Tl[kk][tn * 4 + i];
            #pragma unroll
            for (int i = 0; i < 4; i++) wv[i] = Wl[kk][tj * 4 + i];
            #pragma unroll
            for (int i = 0; i < 4; i++)
                #pragma unroll
                for (int q = 0; q < 4; q++) acc[i][q] += tv[i] * wv[q];
        }
        __syncthreads();
    }
    // plain stores to disjoint per-ks partials (float4, 16B-aligned)
    size_t pbase = (size_t)(ks * NI) * JTOT;
    #pragma unroll
    for (int i = 0; i < 4; i++) {
        int nn = tn * 4 + i;
        int j = j0 + tj * 4;
        float4 st = make_float4(acc[i][0], acc[i][1], acc[i][2], acc[i][3]);
        *(float4*)&partial[pbase + (size_t)nn * JTOT + j] = st;
    }
}

// ========== kernel 2: reduce partials + bias -> permuted att_p ==========
__global__ __launch_bounds__(256) void reduce_attn(const float* __restrict__ partial,
                                                   const float* __restrict__ b,
                                                   float* __restrict__ att_p) {
    int n = blockIdx.y;
    int j = blockIdx.x * 256 + threadIdx.x;
    if (j >= AL) return;
    float s = b[j];
    #pragma unroll
    for (int ks = 0; ks < KSPLIT; ks++)
        s += partial[(size_t)(ks * NI + n) * JTOT + j];
    att_p[(size_t)n * ALP + perm(j)] = s;
}

// ========== kernel 3: fused per-pixel head + block argmax ==========
// All weights are block-uniform (depend only on n = blockIdx.y) -> read them
// through the uniform global pointer so the compiler scalarizes to s_load and
// folds SGPR operands straight into v_fmac. Zero LDS / zero VMEM for weights.
// NOTE: __launch_bounds__(512, 4) — do NOT raise the min-waves arg: (512,8)
// capped VGPRs at 64 and spilled accumulators to scratch (+211 MB WRITE_SIZE,
// 104 -> 115 us). VGPR=40 at (512,4) is spill-free; occupancy is SGPR-bound
// (~3 blocks/CU at SGPR=112) which is an acceptable price for SGPR weights.
__device__ inline unsigned int mono_f32(float f) {
    unsigned int u = __float_as_uint(f);
    return (u & 0x80000000u) ? ~u : (u | 0x80000000u);
}

__global__ __launch_bounds__(512, 4) void pixel_head(const float* __restrict__ bases_full,
                                                     const float* __restrict__ att_p,
                                                     const float* __restrict__ locations,
                                                     const float* __restrict__ soi,
                                                     const int* __restrict__ fpn,
                                                     float* __restrict__ out_logits,
                                                     unsigned long long* __restrict__ partial) {
    __shared__ unsigned long long red[8][NKP];
    int n = blockIdx.y, bx = blockIdx.x, tid = threadIdx.x;
    const float* wn = att_p + (size_t)n * ALP;       // block-uniform base

    int p0 = bx * PXB + tid;
    bool valid = p0 < HW;
    int pc = valid ? p0 : 0;
    int y = pc / WDIM, x = pc - y * WDIM;

    float inv = 1.0f / soi[fpn[n]];
    float lx = locations[2 * n], ly = locations[2 * n + 1];
    float cx = (lx - (float)(x * 8 + 4)) * inv;
    float cy = (ly - (float)(y * 8 + 4)) * inv;

    // issue first bases loads early so latency hides under the offsets FMAs
    const float* bp = bases_full + pc;
    float q0 = bp[0], q1 = bp[HW], q2 = bp[2 * (size_t)HW], q3 = bp[3 * (size_t)HW];

    // ---- layer 0: h = relu(W0 x + b0), c-outer streaming, scalar weights ----
    float h[32];
    {
        const float4* br  = (const float4*)(wn + TB0);
        const float4* w0r = (const float4*)(wn + TW0);
        const float4* w1r = (const float4*)(wn + TW0 + 32);
        #pragma unroll
        for (int g = 0; g < 8; g++) {
            float4 b4 = br[g], wv = w0r[g], wu = w1r[g];
            h[4*g+0] = b4.x + wv.x * cx + wu.x * cy;
            h[4*g+1] = b4.y + wv.y * cx + wu.y * cy;
            h[4*g+2] = b4.z + wv.z * cx + wu.z * cy;
            h[4*g+3] = b4.w + wv.w * cx + wu.w * cy;
        }
    }
    // 4-deep rolling prefetch over the 32 bases channels
    #pragma unroll 2
    for (int c0 = 0; c0 < 32; c0 += 4) {
        float n0 = 0.f, n1 = 0.f, n2 = 0.f, n3 = 0.f;
        if (c0 + 4 < 32) {
            n0 = bp[(size_t)(c0 + 4) * HW];
            n1 = bp[(size_t)(c0 + 5) * HW];
            n2 = bp[(size_t)(c0 + 6) * HW];
            n3 = bp[(size_t)(c0 + 7) * HW];
        }
        float qq[4] = {q0, q1, q2, q3};
        #pragma unroll
        for (int u = 0; u < 4; u++) {
            float bv = qq[u];
            const float4* wr = (const float4*)(wn + TW0 + (c0 + u + 2) * 32);
            #pragma unroll
            for (int g = 0; g < 8; g++) {
                float4 wv = wr[g];
                h[4*g+0] += wv.x * bv;
                h[4*g+1] += wv.y * bv;
                h[4*g+2] += wv.z * bv;
                h[4*g+3] += wv.w * bv;
            }
        }
        q0 = n0; q1 = n1; q2 = n2; q3 = n3;
    }
    #pragma unroll
    for (int o = 0; o < 32; o++) h[o] = fmaxf(h[o], 0.0f);

    // ---- layer 1: scalar weights via uniform global pointer ----
    float gg[32];
    {
        const float4* br = (const float4*)(wn + TB1);
        #pragma unroll
        for (int g = 0; g < 8; g++) {
            float4 b4 = br[g];
            gg[4*g+0] = b4.x; gg[4*g+1] = b4.y; gg[4*g+2] = b4.z; gg[4*g+3] = b4.w;
        }
    }
    #pragma unroll 4
    for (int c = 0; c < 32; c++) {
        float xv = h[c];
        const float4* wr = (const float4*)(wn + TW1 + c * 32);
        #pragma unroll
        for (int g = 0; g < 8; g++) {
            float4 wv = wr[g];
            gg[4*g+0] += wv.x * xv;
            gg[4*g+1] += wv.y * xv;
            gg[4*g+2] += wv.z * xv;
            gg[4*g+3] += wv.w * xv;
        }
    }
    #pragma unroll
    for (int o = 0; o < 32; o++) gg[o] = fmaxf(gg[o], 0.0f);

    // ---- layer 2: scalar weights; store logits + fused per-k argmax ----
    // Wave argmax: 32-bit fp max butterfly, then ballot + ffs for the winning
    // lane (lowest lane = smallest pixel index = numpy first-occurrence).
    size_t obase = (size_t)n * NKP * HW;
    int wid = tid >> 6, lane = tid & 63;
    #pragma unroll
    for (int k = 0; k < NKP; k++) {
        const float4* wr = (const float4*)(wn + TW2 + k * 32);
        float s = wn[TB2 + k];
        #pragma unroll
        for (int g = 0; g < 8; g++) {
            float4 wv = wr[g];
            s += wv.x * gg[4*g+0] + wv.y * gg[4*g+1] + wv.z * gg[4*g+2] + wv.w * gg[4*g+3];
        }
        if (valid)
            __builtin_nontemporal_store(s, &out_logits[obase + (size_t)k * HW + p0]);
        float sm = valid ? s : -__builtin_inff();
        float m = sm;
        #pragma unroll
        for (int off = 32; off > 0; off >>= 1)
            m = fmaxf(m, __shfl_xor(m, off));
        unsigned long long ball = __ballot(sm == m);
        if (lane == 0) {
            int winlane = __ffsll((unsigned long long)ball) - 1;
            unsigned pix = (unsigned)(bx * PXB + (wid << 6) + winlane);
            red[wid][k] = ((unsigned long long)mono_f32(m) << 32) |
                          (unsigned long long)(0xFFFFFFFFu - pix);
        }
    }
    __syncthreads();
    if (tid < NKP) {
        unsigned long long m = red[0][tid];
        #pragma unroll
        for (int ww = 1; ww < 8; ww++)
            if (red[ww][tid] > m) m = red[ww][tid];
        partial[((size_t)n * NKP + tid) * NBX + bx] = m;
    }
}

// ========== kernel 4: final argmax reduce + keypoint ==========
__global__ __launch_bounds__(64) void kp_final(const unsigned long long* __restrict__ partial,
                                               const float* __restrict__ bases_full,
                                               float* __restrict__ kp_out) {
    int b = blockIdx.x;
    int n = b / NKP, k = b % NKP;
    int lane = threadIdx.x;
    unsigned long long v = (lane < NBX) ? partial[((size_t)n * NKP + k) * NBX + lane] : 0ull;
    #pragma unroll
    for (int off = 32; off > 0; off >>= 1) {
        unsigned long long o = __shfl_down(v, off);
        if (o > v) v = o;
    }
    if (lane == 0) {
        int p = (int)(0xFFFFFFFFu - (unsigned)(v & 0xFFFFFFFFull));
        int yy = p / WDIM;
        int xx = p - yy * WDIM;
        float kx = bases_full[(size_t)(NBASES + 2 * k) * HW + p] + (float)(xx * 8 + 4);
        float ky = bases_full[(size_t)(NBASES + 2 * k + 1) * HW + p] + (float)(yy * 8 + 4);
        kp_out[((size_t)n * NKP + k) * 2 + 0] = kx;
        kp_out[((size_t)n * NKP + k) * 2 + 1] = ky;
    }
}

extern "C" void kernel_launch(void* const* d_in, const int* in_sizes, int n_in,
                              void* d_out, int out_size, void* d_ws, size_t ws_size,
                              hipStream_t stream) {
    const float* bases_full = (const float*)d_in[0];
    const float* top_feats  = (const float*)d_in[1];
    const float* locations  = (const float*)d_in[2];
    const float* atten_W    = (const float*)d_in[3];
    const float* atten_b    = (const float*)d_in[4];
    const float* soi        = (const float*)d_in[5];
    const int*   fpn        = (const int*)d_in[6];
    float* out   = (float*)d_out;
    float* att_p = (float*)((char*)d_ws + ATT_OFF);
    unsigned long long* argp = (unsigned long long*)((char*)d_ws + ARGP_OFF);
    float* gemmp = (float*)((char*)d_ws + GEMMP_OFF);

    gemm_attn<<<NJT * KSPLIT, 256, 0, stream>>>(top_feats, atten_W, gemmp);

    dim3 gr((AL + 255) / 256, NI);   // 11 x 64
    reduce_attn<<<gr, 256, 0, stream>>>(gemmp, atten_b, att_p);

    dim3 g2(NBX, NI);   // 30 x 64
    pixel_head<<<g2, 512, 0, stream>>>(bases_full, att_p, locations, soi, fpn, out, argp);

    float* kp_out = out + (size_t)NI * NKP * HW;
    kp_final<<<NI * NKP, 64, 0, stream>>>(argp, bases_full, kp_out);
}